// Round 1
// 1295.771 us; speedup vs baseline: 1.2598x; 1.2598x over previous
//
#include <hip/hip_runtime.h>
#include <hip/hip_bf16.h>
#include <stdint.h>

#define NR 10000          // real rows/cols
#define MP 10112          // padded: 79*128 = 158*64
#define MT256 40          // ceil(MP/256) -- last M-tile guarded

typedef __attribute__((ext_vector_type(8))) __bf16 bf16x8;
typedef __attribute__((ext_vector_type(4))) float  f4_t;

__device__ __forceinline__ uint16_t f2bf(float f) {
    uint32_t u = __builtin_bit_cast(uint32_t, f);
    uint32_t r = u + 0x7FFFu + ((u >> 16) & 1u);   // RTNE
    return (uint16_t)(r >> 16);
}

// ---------------- conversion kernels ----------------

// adj (10000x10000 f32) -> adjb (MP x MP bf16, zero padded)
__global__ void conv_adj(const float* __restrict__ src, uint16_t* __restrict__ dst) {
    int row = blockIdx.y;
    int j0  = (blockIdx.x * 256 + threadIdx.x) * 8;
    if (j0 >= MP) return;
    uint32_t p0 = 0, p1 = 0, p2 = 0, p3 = 0;
    if (row < NR && j0 < NR) {
        const float* p = src + (size_t)row * NR + j0;
        float4 a = *(const float4*)p;
        float4 b = *(const float4*)(p + 4);
        p0 = (uint32_t)f2bf(a.x) | ((uint32_t)f2bf(a.y) << 16);
        p1 = (uint32_t)f2bf(a.z) | ((uint32_t)f2bf(a.w) << 16);
        p2 = (uint32_t)f2bf(b.x) | ((uint32_t)f2bf(b.y) << 16);
        p3 = (uint32_t)f2bf(b.z) | ((uint32_t)f2bf(b.w) << 16);
    }
    uint4 pk; pk.x = p0; pk.y = p1; pk.z = p2; pk.w = p3;
    *(uint4*)&dst[(size_t)row * MP + j0] = pk;
}

// x (10000x512 f32) -> xb (MP x 512 bf16, zero padded rows)
__global__ void conv_x(const float* __restrict__ src, uint16_t* __restrict__ dst) {
    int gid = blockIdx.x * 256 + threadIdx.x;
    int row = gid >> 6;
    int j0  = (gid & 63) * 8;
    uint32_t p0 = 0, p1 = 0, p2 = 0, p3 = 0;
    if (row < NR) {
        const float* p = src + (size_t)row * 512 + j0;
        float4 a = *(const float4*)p;
        float4 b = *(const float4*)(p + 4);
        p0 = (uint32_t)f2bf(a.x) | ((uint32_t)f2bf(a.y) << 16);
        p1 = (uint32_t)f2bf(a.z) | ((uint32_t)f2bf(a.w) << 16);
        p2 = (uint32_t)f2bf(b.x) | ((uint32_t)f2bf(b.y) << 16);
        p3 = (uint32_t)f2bf(b.z) | ((uint32_t)f2bf(b.w) << 16);
    }
    uint4 pk; pk.x = p0; pk.y = p1; pk.z = p2; pk.w = p3;
    *(uint4*)&dst[(size_t)row * 512 + j0] = pk;
}

// W (K x Nsrc f32) -> WT (NP x K bf16); rows n >= Nsrc zeroed. grid.y = NP, block 128.
__global__ void conv_wT(const float* __restrict__ src, uint16_t* __restrict__ dst,
                        int K, int Nsrc) {
    int n  = blockIdx.y;
    int k0 = threadIdx.x * 8;
    if (k0 >= K) return;
    uint16_t h[8];
    #pragma unroll
    for (int i = 0; i < 8; ++i) h[i] = 0;
    if (n < Nsrc) {
        #pragma unroll
        for (int i = 0; i < 8; ++i)
            h[i] = f2bf(src[(size_t)(k0 + i) * Nsrc + n]);
    }
    uint4 pk;
    pk.x = (uint32_t)h[0] | ((uint32_t)h[1] << 16);
    pk.y = (uint32_t)h[2] | ((uint32_t)h[3] << 16);
    pk.z = (uint32_t)h[4] | ((uint32_t)h[5] << 16);
    pk.w = (uint32_t)h[6] | ((uint32_t)h[7] << 16);
    *(uint4*)&dst[(size_t)n * K + k0] = pk;
}

// ---------------- GEMM: C = A(MxK) * BT(NxK)^T  (128x128, feature/final) ----------------
template<int RELU, int BF16OUT, int TSTORE, int GUARD, int SPLIT>
__global__ __launch_bounds__(256)
void gemm_bt(const uint16_t* __restrict__ A, const uint16_t* __restrict__ BT,
             void* __restrict__ Cv, const float* __restrict__ bias,
             int lda, int ldb, int ldc, int K, int Mstore, int Nstore,
             long sstride)
{
    __shared__ uint16_t sA[8192];
    __shared__ uint16_t sB[8192];
    const int tid  = threadIdx.x;
    const int lane = tid & 63;
    const int wv   = tid >> 6;
    const int wm   = wv >> 1;
    const int wn   = wv & 1;
    const long tileM = (long)blockIdx.x * 128;
    const long tileN = (long)blockIdx.y * 128;

    const uint16_t* aSrc[4];
    const uint16_t* bSrc[4];
    uint16_t* aDst[4];
    uint16_t* bDst[4];
    #pragma unroll
    for (int t = 0; t < 4; ++t) {
        int c    = t * 256 + tid;
        int rg   = (c >> 6) & 7;
        int kk   = c >> 9;
        int row  = rg * 16 + (lane & 15);
        int kcol = kk * 32 + ((lane >> 4) & 3) * 8;
        aSrc[t] = A  + (tileM + row) * (long)lda + kcol;
        bSrc[t] = BT + (tileN + row) * (long)ldb + kcol;
        aDst[t] = &sA[c * 8];
        bDst[t] = &sB[c * 8];
    }

    f4_t acc[4][4];
    #pragma unroll
    for (int mi = 0; mi < 4; ++mi)
        #pragma unroll
        for (int ni = 0; ni < 4; ++ni)
            acc[mi][ni] = {0.0f, 0.0f, 0.0f, 0.0f};

    const int nIterTot = K >> 6;
    int it0 = 0, it1 = nIterTot;
    if (SPLIT) {
        it0 = (int)(((long)blockIdx.z * nIterTot) / gridDim.z);
        it1 = (int)(((long)(blockIdx.z + 1) * nIterTot) / gridDim.z);
    }
    long kOff = (long)it0 * 64;
    for (int it = it0; it < it1; ++it) {
        __syncthreads();
        #pragma unroll
        for (int t = 0; t < 4; ++t) {
            __builtin_amdgcn_global_load_lds(
                (__attribute__((address_space(1))) void*)(aSrc[t] + kOff),
                (__attribute__((address_space(3))) void*)aDst[t], 16, 0, 0);
            __builtin_amdgcn_global_load_lds(
                (__attribute__((address_space(1))) void*)(bSrc[t] + kOff),
                (__attribute__((address_space(3))) void*)bDst[t], 16, 0, 0);
        }
        __syncthreads();
        #pragma unroll
        for (int kk = 0; kk < 2; ++kk) {
            bf16x8 af[4], bb[4];
            #pragma unroll
            for (int mi = 0; mi < 4; ++mi)
                af[mi] = *(const bf16x8*)&sA[((kk * 8 + wm * 4 + mi) * 64 + lane) * 8];
            #pragma unroll
            for (int ni = 0; ni < 4; ++ni)
                bb[ni] = *(const bf16x8*)&sB[((kk * 8 + wn * 4 + ni) * 64 + lane) * 8];
            #pragma unroll
            for (int mi = 0; mi < 4; ++mi)
                #pragma unroll
                for (int ni = 0; ni < 4; ++ni)
                    acc[mi][ni] = __builtin_amdgcn_mfma_f32_16x16x32_bf16(
                        af[mi], bb[ni], acc[mi][ni], 0, 0, 0);
        }
        kOff += 64;
    }

    const int colLoc = wn * 64 + (lane & 15);
    const int rowLoc = wm * 64 + ((lane >> 4) & 3) * 4;
    #pragma unroll
    for (int ni = 0; ni < 4; ++ni) {
        long col = tileN + colLoc + ni * 16;
        float bv = 0.0f;
        if (!SPLIT && bias) { if (!GUARD || col < Nstore) bv = bias[col]; }
        #pragma unroll
        for (int mi = 0; mi < 4; ++mi) {
            long row = tileM + rowLoc + mi * 16;
            f4_t v = acc[mi][ni];
            float f[4];
            #pragma unroll
            for (int r = 0; r < 4; ++r) {
                f[r] = v[r] + bv;
                if (RELU) f[r] = fmaxf(f[r], 0.0f);
            }
            if (SPLIT) {
                float* C = (float*)Cv + (long)blockIdx.z * sstride;
                #pragma unroll
                for (int r = 0; r < 4; ++r)
                    C[(row + r) * (long)ldc + col] = f[r];
            } else if (TSTORE) {
                uint16_t* C = (uint16_t*)Cv;
                uint2 pk;
                pk.x = (uint32_t)f2bf(f[0]) | ((uint32_t)f2bf(f[1]) << 16);
                pk.y = (uint32_t)f2bf(f[2]) | ((uint32_t)f2bf(f[3]) << 16);
                *(uint2*)&C[col * (long)ldc + row] = pk;
            } else if (BF16OUT) {
                uint16_t* C = (uint16_t*)Cv;
                #pragma unroll
                for (int r = 0; r < 4; ++r)
                    C[(row + r) * (long)ldc + col] = f2bf(f[r]);
            } else {
                float* C = (float*)Cv;
                #pragma unroll
                for (int r = 0; r < 4; ++r)
                    if (!GUARD || ((row + r) < Mstore && col < Nstore))
                        C[(row + r) * (long)ldc + col] = f[r];
            }
        }
    }
}

// ---------------- GEMM256: 256x256 tile, BK=32, 8 waves, 4-deep counted-vmcnt pipeline ----
// C = A(MxK) * BT(NxK)^T. Fragment-major LDS (conflict-free), global_load_lds width 16,
// s_waitcnt vmcnt(12) keeps 3 K-tiles in flight (never drains in main loop), raw s_barrier,
// setprio around the MFMA cluster, XCD-chunked n-fastest block decode (A-panel L2 locality).
// SPLIT: fp32 partial at Cv + z*sstride (no bias/relu); else bf16 out with bias(+relu).
// M-tile 39 is guarded at Mst (staging reads past adjb stay inside workspace; rows >= Mst dropped).
template<int RELU, int SPLIT>
__global__ __launch_bounds__(512, 2)
void gemm256(const uint16_t* __restrict__ A, const uint16_t* __restrict__ BT,
             void* __restrict__ Cv, const float* __restrict__ bias,
             int lda, int ldb, int ldc, int K, int nTn, int S,
             long sstride, int Mst)
{
    __shared__ uint16_t lds[4][16384];   // 4 bufs x (A 16KB + B 16KB)

    // bijective XCD-chunk swizzle (m204), then decode with n-tile fastest.
    const int nb  = (int)gridDim.x;
    const int id  = (int)blockIdx.x;
    const int q   = nb >> 3;
    const int rem = nb & 7;
    const int xcd = id & 7, pos = id >> 3;
    const int wg  = (xcd < rem) ? xcd * (q + 1) + pos
                                : rem * (q + 1) + (xcd - rem) * q + pos;
    const int n_t = wg % nTn;
    const int mz  = wg / nTn;
    const int m_t = mz % MT256;
    const int z   = mz / MT256;

    const long tileM = (long)m_t * 256;
    const long tileN = (long)n_t * 256;

    const int tid  = threadIdx.x;
    const int lane = tid & 63;
    const int wv   = tid >> 6;     // 0..7
    const int wm   = wv >> 2;      // 0..1 (M half)
    const int wn   = wv & 3;       // 0..3 (N quarter)

    // staging: 32 fragment-blocks/buffer (16 A + 16 B), 1KB each; wave wv does blocks j*8+wv.
    // LDS[g*512 + lane*8 + e] = M[tile + (g&15)*16 + (lane&15)][k + ((lane>>4)&3)*8 + e]
    const uint16_t* gsrc[4];
    int doff[4];
    #pragma unroll
    for (int j = 0; j < 4; ++j) {
        int g   = j * 8 + wv;
        int row = (g & 15) * 16 + (lane & 15);
        int kc  = ((lane >> 4) & 3) * 8;
        gsrc[j] = (g < 16) ? (A  + (tileM + row) * (long)lda + kc)
                           : (BT + (tileN + row) * (long)ldb + kc);
        doff[j] = g * 512 + lane * 8;
    }

    const int KT  = K >> 5;                       // K-tiles of 32
    const int kt0 = (int)(((long)z * KT) / S);
    const int kt1 = (int)(((long)(z + 1) * KT) / S);
    const int nt  = kt1 - kt0;
    const long kb = (long)kt0 * 32;

    f4_t acc[8][4];
    #pragma unroll
    for (int mi = 0; mi < 8; ++mi)
        #pragma unroll
        for (int ni = 0; ni < 4; ++ni)
            acc[mi][ni] = {0.0f, 0.0f, 0.0f, 0.0f};

    auto issue = [&](int t) {
        int p   = t & 3;
        long ko = kb + (long)t * 32;
        #pragma unroll
        for (int j = 0; j < 4; ++j)
            __builtin_amdgcn_global_load_lds(
                (__attribute__((address_space(1))) void*)(gsrc[j] + ko),
                (__attribute__((address_space(3))) void*)(&lds[p][doff[j]]),
                16, 0, 0);
    };

    issue(0); issue(1); issue(2);    // prologue: 3 tiles in flight (12 loads/wave)

    for (int t = 0; t < nt; ++t) {
        if (t + 3 < nt) {
            issue(t + 3);                                    // overwrites buf read at t-1 (safe past trailing barrier)
            asm volatile("s_waitcnt vmcnt(12)" ::: "memory"); // oldest 4 (= tile t) complete; 3 tiles stay in flight
        } else {
            asm volatile("s_waitcnt vmcnt(0)" ::: "memory");  // tail (last 3 iters only)
        }
        asm volatile("s_barrier" ::: "memory");

        const uint16_t* bp = &lds[t & 3][0];
        bf16x8 af[8], bb[4];
        #pragma unroll
        for (int mi = 0; mi < 8; ++mi)
            af[mi] = *(const bf16x8*)(bp + (wm * 8 + mi) * 512 + lane * 8);
        #pragma unroll
        for (int ni = 0; ni < 4; ++ni)
            bb[ni] = *(const bf16x8*)(bp + 8192 + (wn * 4 + ni) * 512 + lane * 8);

        __builtin_amdgcn_s_setprio(1);
        #pragma unroll
        for (int mi = 0; mi < 8; ++mi)
            #pragma unroll
            for (int ni = 0; ni < 4; ++ni)
                acc[mi][ni] = __builtin_amdgcn_mfma_f32_16x16x32_bf16(
                    af[mi], bb[ni], acc[mi][ni], 0, 0, 0);
        __builtin_amdgcn_s_setprio(0);

        asm volatile("s_barrier" ::: "memory");   // all waves done reading buf[t&3] before t+4 issue
    }

    // epilogue: row = tileM + wm*128 + mi*16 + (lane>>4)*4 + rr ; col = tileN + wn*64 + ni*16 + (lane&15)
    const int colL = lane & 15;
    const int rowL = ((lane >> 4) & 3) * 4;
    #pragma unroll
    for (int ni = 0; ni < 4; ++ni) {
        long col = tileN + wn * 64 + ni * 16 + colL;
        float bv = 0.0f;
        if (!SPLIT && bias) bv = bias[col];
        #pragma unroll
        for (int mi = 0; mi < 8; ++mi) {
            long row = tileM + wm * 128 + mi * 16 + rowL;
            f4_t v = acc[mi][ni];
            #pragma unroll
            for (int rr = 0; rr < 4; ++rr) {
                if (row + rr < Mst) {
                    float f = v[rr] + bv;
                    if (RELU) f = fmaxf(f, 0.0f);
                    if (SPLIT)
                        ((float*)Cv + (long)z * sstride)[(row + rr) * (long)ldc + col] = f;
                    else
                        ((uint16_t*)Cv)[(row + rr) * (long)ldc + col] = f2bf(f);
                }
            }
        }
    }
}

// ---------------- split-K reduction: sum S partials, +bias, relu, bf16 ----------------
__global__ __launch_bounds__(256)
void reduce_relu(const float* __restrict__ part, const float* __restrict__ bias,
                 uint16_t* __restrict__ h, int logN, int S, long MN)
{
    long base = ((long)blockIdx.x * 256 + threadIdx.x) * 8;
    int col = (int)(base & ((1 << logN) - 1));
    float4 s0 = *(const float4*)(part + base);
    float4 s1 = *(const float4*)(part + base + 4);
    for (int s = 1; s < S; ++s) {
        const float* p = part + (long)s * MN + base;
        float4 a = *(const float4*)p;
        float4 b = *(const float4*)(p + 4);
        s0.x += a.x; s0.y += a.y; s0.z += a.z; s0.w += a.w;
        s1.x += b.x; s1.y += b.y; s1.z += b.z; s1.w += b.w;
    }
    float f[8] = { s0.x, s0.y, s0.z, s0.w, s1.x, s1.y, s1.z, s1.w };
    #pragma unroll
    for (int i = 0; i < 8; ++i)
        f[i] = fmaxf(f[i] + bias[col + i], 0.0f);
    uint4 pk;
    pk.x = (uint32_t)f2bf(f[0]) | ((uint32_t)f2bf(f[1]) << 16);
    pk.y = (uint32_t)f2bf(f[2]) | ((uint32_t)f2bf(f[3]) << 16);
    pk.z = (uint32_t)f2bf(f[4]) | ((uint32_t)f2bf(f[5]) << 16);
    pk.w = (uint32_t)f2bf(f[6]) | ((uint32_t)f2bf(f[7]) << 16);
    *(uint4*)&h[base] = pk;
}

// ---------------- launch ----------------

extern "C" void kernel_launch(void* const* d_in, const int* in_sizes, int n_in,
                              void* d_out, int out_size, void* d_ws, size_t ws_size,
                              hipStream_t stream)
{
    const float* x   = (const float*)d_in[0];
    const float* adj = (const float*)d_in[1];
    const float* W1  = (const float*)d_in[2];
    const float* b1  = (const float*)d_in[3];
    const float* W2  = (const float*)d_in[4];
    const float* b2  = (const float*)d_in[5];
    const float* W3  = (const float*)d_in[6];
    const float* b3  = (const float*)d_in[7];
    const float* Wf  = (const float*)d_in[8];
    const float* bf_ = (const float*)d_in[9];
    float* out = (float*)d_out;

    char* w0 = (char*)d_ws;
    char* w = w0;
    uint16_t* adjb = (uint16_t*)w;  w += (size_t)MP * MP * 2;        // 204.5 MB
    uint16_t* w1t  = (uint16_t*)w;  w += (size_t)512 * 512 * 2;
    uint16_t* w2t  = (uint16_t*)w;  w += (size_t)512 * 512 * 2;
    uint16_t* w3t  = (uint16_t*)w;  w += (size_t)1024 * 512 * 2;
    uint16_t* wft  = (uint16_t*)w;  w += (size_t)256 * 1024 * 2;
    uint16_t* poolP = (uint16_t*)w; w += (size_t)1024 * MP * 2;      // 20.7 MB each
    uint16_t* poolQ = (uint16_t*)w; w += (size_t)1024 * MP * 2;
    uint16_t* poolR = (uint16_t*)w; w += (size_t)1024 * MP * 2;
    float* partial  = (float*)w;
    size_t base_need = (size_t)(w - w0);
    size_t pu = (size_t)MP * 512 * 4;              // 20.7 MB split-unit

    // host-side deterministic split-K config (graph-safe).
    // Grid sizing at 1 block/CU (128KB LDS): S12=3 -> 240 blocks (94% fill of 256 CUs),
    // S3=3 -> 480 (2 waves of 240); fallbacks shrink partial footprint.
    int S12, S3;
    if      (ws_size >= base_need + 6 * pu) { S12 = 3; S3 = 3; }
    else if (ws_size >= base_need + 4 * pu) { S12 = 3; S3 = 2; }   // same footprint as prior version
    else if (ws_size >= base_need + 3 * pu) { S12 = 3; S3 = 1; }
    else                                    { S12 = 1; S3 = 1; }

    uint16_t* xb  = poolP;   // MP x 512
    uint16_t* z1t = poolQ;   // 512 x MP
    uint16_t* h1  = poolR;   // MP x 512
    uint16_t* z2t = poolP;   // 512 x MP
    uint16_t* h2  = poolQ;   // MP x 512
    uint16_t* z3t = poolR;   // 1024 x MP
    uint16_t* h3  = poolP;   // MP x 1024

    // conversions
    conv_adj<<<dim3(5, MP), 256, 0, stream>>>(adj, adjb);
    conv_x<<<dim3(MP / 4), 256, 0, stream>>>(x, xb);
    conv_wT<<<dim3(1, 512),  128, 0, stream>>>(W1, w1t, 512, 512);
    conv_wT<<<dim3(1, 512),  128, 0, stream>>>(W2, w2t, 512, 512);
    conv_wT<<<dim3(1, 1024), 128, 0, stream>>>(W3, w3t, 512, 1024);
    conv_wT<<<dim3(1, 256),  128, 0, stream>>>(Wf, wft, 1024, 151);

    const long MN512  = (long)MP * 512;
    const long MN1024 = (long)MP * 1024;

    auto adj_gemm = [&](uint16_t* zt, uint16_t* h, const float* b, int nTn,
                        int N, int logN, int S, long MN) {
        int blocks = MT256 * nTn * S;
        if (S > 1) {
            gemm256<0,1><<<dim3(blocks), 512, 0, stream>>>(
                adjb, zt, partial, nullptr, MP, MP, N, MP, nTn, S, MN, MP);
            reduce_relu<<<dim3((int)(MN / 2048)), 256, 0, stream>>>(partial, b, h, logN, S, MN);
        } else {
            gemm256<1,0><<<dim3(blocks), 512, 0, stream>>>(
                adjb, zt, h, b, MP, MP, N, MP, nTn, 1, 0, MP);
        }
    };

    // layer 1
    gemm_bt<0,1,1,0,0><<<dim3(79, 4), 256, 0, stream>>>(xb, w1t, z1t, nullptr, 512, 512, MP, 512, 0, 0, 0);
    adj_gemm(z1t, h1, b1, 2, 512, 9, S12, MN512);
    // layer 2
    gemm_bt<0,1,1,0,0><<<dim3(79, 4), 256, 0, stream>>>(h1, w2t, z2t, nullptr, 512, 512, MP, 512, 0, 0, 0);
    adj_gemm(z2t, h2, b2, 2, 512, 9, S12, MN512);
    // layer 3 (N = 1024)
    gemm_bt<0,1,1,0,0><<<dim3(79, 8), 256, 0, stream>>>(h2, w3t, z3t, nullptr, 512, 512, MP, 512, 0, 0, 0);
    adj_gemm(z3t, h3, b3, 4, 1024, 10, S3, MN1024);
    // final: out = h3 @ Wf + bf (fp32, guarded 10000 x 151)
    gemm_bt<0,0,0,1,0><<<dim3(79, 2), 256, 0, stream>>>(h3, wft, out, bf_, 1024, 1024, 151, 1024, NR, 151, 0);
}

// Round 2
// 1274.046 us; speedup vs baseline: 1.2812x; 1.0171x over previous
//
#include <hip/hip_runtime.h>
#include <hip/hip_bf16.h>
#include <stdint.h>

#define NR 10000          // real rows/cols
#define MP 10112          // padded: 79*128 = 158*64
#define MT256 40          // ceil(MP/256) -- last M-tile guarded

typedef __attribute__((ext_vector_type(8))) __bf16 bf16x8;
typedef __attribute__((ext_vector_type(4))) float  f4_t;

__device__ __forceinline__ uint16_t f2bf(float f) {
    uint32_t u = __builtin_bit_cast(uint32_t, f);
    uint32_t r = u + 0x7FFFu + ((u >> 16) & 1u);   // RTNE
    return (uint16_t)(r >> 16);
}

// ---------------- conversion kernels ----------------

// adj (10000x10000 f32) -> adjb (MP x MP bf16, zero padded)
__global__ void conv_adj(const float* __restrict__ src, uint16_t* __restrict__ dst) {
    int row = blockIdx.y;
    int j0  = (blockIdx.x * 256 + threadIdx.x) * 8;
    if (j0 >= MP) return;
    uint32_t p0 = 0, p1 = 0, p2 = 0, p3 = 0;
    if (row < NR && j0 < NR) {
        const float* p = src + (size_t)row * NR + j0;
        float4 a = *(const float4*)p;
        float4 b = *(const float4*)(p + 4);
        p0 = (uint32_t)f2bf(a.x) | ((uint32_t)f2bf(a.y) << 16);
        p1 = (uint32_t)f2bf(a.z) | ((uint32_t)f2bf(a.w) << 16);
        p2 = (uint32_t)f2bf(b.x) | ((uint32_t)f2bf(b.y) << 16);
        p3 = (uint32_t)f2bf(b.z) | ((uint32_t)f2bf(b.w) << 16);
    }
    uint4 pk; pk.x = p0; pk.y = p1; pk.z = p2; pk.w = p3;
    *(uint4*)&dst[(size_t)row * MP + j0] = pk;
}

// x (10000x512 f32) -> xb (MP x 512 bf16, zero padded rows)
__global__ void conv_x(const float* __restrict__ src, uint16_t* __restrict__ dst) {
    int gid = blockIdx.x * 256 + threadIdx.x;
    int row = gid >> 6;
    int j0  = (gid & 63) * 8;
    uint32_t p0 = 0, p1 = 0, p2 = 0, p3 = 0;
    if (row < NR) {
        const float* p = src + (size_t)row * 512 + j0;
        float4 a = *(const float4*)p;
        float4 b = *(const float4*)(p + 4);
        p0 = (uint32_t)f2bf(a.x) | ((uint32_t)f2bf(a.y) << 16);
        p1 = (uint32_t)f2bf(a.z) | ((uint32_t)f2bf(a.w) << 16);
        p2 = (uint32_t)f2bf(b.x) | ((uint32_t)f2bf(b.y) << 16);
        p3 = (uint32_t)f2bf(b.z) | ((uint32_t)f2bf(b.w) << 16);
    }
    uint4 pk; pk.x = p0; pk.y = p1; pk.z = p2; pk.w = p3;
    *(uint4*)&dst[(size_t)row * 512 + j0] = pk;
}

// W (K x Nsrc f32) -> WT (NP x K bf16); rows n >= Nsrc zeroed. grid.y = NP, block 128.
__global__ void conv_wT(const float* __restrict__ src, uint16_t* __restrict__ dst,
                        int K, int Nsrc) {
    int n  = blockIdx.y;
    int k0 = threadIdx.x * 8;
    if (k0 >= K) return;
    uint16_t h[8];
    #pragma unroll
    for (int i = 0; i < 8; ++i) h[i] = 0;
    if (n < Nsrc) {
        #pragma unroll
        for (int i = 0; i < 8; ++i)
            h[i] = f2bf(src[(size_t)(k0 + i) * Nsrc + n]);
    }
    uint4 pk;
    pk.x = (uint32_t)h[0] | ((uint32_t)h[1] << 16);
    pk.y = (uint32_t)h[2] | ((uint32_t)h[3] << 16);
    pk.z = (uint32_t)h[4] | ((uint32_t)h[5] << 16);
    pk.w = (uint32_t)h[6] | ((uint32_t)h[7] << 16);
    *(uint4*)&dst[(size_t)n * K + k0] = pk;
}

// ---------------- GEMM: C = A(MxK) * BT(NxK)^T  (128x128, feature/final) ----------------
template<int RELU, int BF16OUT, int TSTORE, int GUARD, int SPLIT>
__global__ __launch_bounds__(256)
void gemm_bt(const uint16_t* __restrict__ A, const uint16_t* __restrict__ BT,
             void* __restrict__ Cv, const float* __restrict__ bias,
             int lda, int ldb, int ldc, int K, int Mstore, int Nstore,
             long sstride)
{
    __shared__ uint16_t sA[8192];
    __shared__ uint16_t sB[8192];
    const int tid  = threadIdx.x;
    const int lane = tid & 63;
    const int wv   = tid >> 6;
    const int wm   = wv >> 1;
    const int wn   = wv & 1;
    const long tileM = (long)blockIdx.x * 128;
    const long tileN = (long)blockIdx.y * 128;

    const uint16_t* aSrc[4];
    const uint16_t* bSrc[4];
    uint16_t* aDst[4];
    uint16_t* bDst[4];
    #pragma unroll
    for (int t = 0; t < 4; ++t) {
        int c    = t * 256 + tid;
        int rg   = (c >> 6) & 7;
        int kk   = c >> 9;
        int row  = rg * 16 + (lane & 15);
        int kcol = kk * 32 + ((lane >> 4) & 3) * 8;
        aSrc[t] = A  + (tileM + row) * (long)lda + kcol;
        bSrc[t] = BT + (tileN + row) * (long)ldb + kcol;
        aDst[t] = &sA[c * 8];
        bDst[t] = &sB[c * 8];
    }

    f4_t acc[4][4];
    #pragma unroll
    for (int mi = 0; mi < 4; ++mi)
        #pragma unroll
        for (int ni = 0; ni < 4; ++ni)
            acc[mi][ni] = {0.0f, 0.0f, 0.0f, 0.0f};

    const int nIterTot = K >> 6;
    int it0 = 0, it1 = nIterTot;
    if (SPLIT) {
        it0 = (int)(((long)blockIdx.z * nIterTot) / gridDim.z);
        it1 = (int)(((long)(blockIdx.z + 1) * nIterTot) / gridDim.z);
    }
    long kOff = (long)it0 * 64;
    for (int it = it0; it < it1; ++it) {
        __syncthreads();
        #pragma unroll
        for (int t = 0; t < 4; ++t) {
            __builtin_amdgcn_global_load_lds(
                (__attribute__((address_space(1))) void*)(aSrc[t] + kOff),
                (__attribute__((address_space(3))) void*)aDst[t], 16, 0, 0);
            __builtin_amdgcn_global_load_lds(
                (__attribute__((address_space(1))) void*)(bSrc[t] + kOff),
                (__attribute__((address_space(3))) void*)bDst[t], 16, 0, 0);
        }
        __syncthreads();
        #pragma unroll
        for (int kk = 0; kk < 2; ++kk) {
            bf16x8 af[4], bb[4];
            #pragma unroll
            for (int mi = 0; mi < 4; ++mi)
                af[mi] = *(const bf16x8*)&sA[((kk * 8 + wm * 4 + mi) * 64 + lane) * 8];
            #pragma unroll
            for (int ni = 0; ni < 4; ++ni)
                bb[ni] = *(const bf16x8*)&sB[((kk * 8 + wn * 4 + ni) * 64 + lane) * 8];
            #pragma unroll
            for (int mi = 0; mi < 4; ++mi)
                #pragma unroll
                for (int ni = 0; ni < 4; ++ni)
                    acc[mi][ni] = __builtin_amdgcn_mfma_f32_16x16x32_bf16(
                        af[mi], bb[ni], acc[mi][ni], 0, 0, 0);
        }
        kOff += 64;
    }

    const int colLoc = wn * 64 + (lane & 15);
    const int rowLoc = wm * 64 + ((lane >> 4) & 3) * 4;
    #pragma unroll
    for (int ni = 0; ni < 4; ++ni) {
        long col = tileN + colLoc + ni * 16;
        float bv = 0.0f;
        if (!SPLIT && bias) { if (!GUARD || col < Nstore) bv = bias[col]; }
        #pragma unroll
        for (int mi = 0; mi < 4; ++mi) {
            long row = tileM + rowLoc + mi * 16;
            f4_t v = acc[mi][ni];
            float f[4];
            #pragma unroll
            for (int r = 0; r < 4; ++r) {
                f[r] = v[r] + bv;
                if (RELU) f[r] = fmaxf(f[r], 0.0f);
            }
            if (SPLIT) {
                float* C = (float*)Cv + (long)blockIdx.z * sstride;
                #pragma unroll
                for (int r = 0; r < 4; ++r)
                    C[(row + r) * (long)ldc + col] = f[r];
            } else if (TSTORE) {
                uint16_t* C = (uint16_t*)Cv;
                uint2 pk;
                pk.x = (uint32_t)f2bf(f[0]) | ((uint32_t)f2bf(f[1]) << 16);
                pk.y = (uint32_t)f2bf(f[2]) | ((uint32_t)f2bf(f[3]) << 16);
                *(uint2*)&C[col * (long)ldc + row] = pk;
            } else if (BF16OUT) {
                uint16_t* C = (uint16_t*)Cv;
                #pragma unroll
                for (int r = 0; r < 4; ++r)
                    C[(row + r) * (long)ldc + col] = f2bf(f[r]);
            } else {
                float* C = (float*)Cv;
                #pragma unroll
                for (int r = 0; r < 4; ++r)
                    if (!GUARD || ((row + r) < Mstore && col < Nstore))
                        C[(row + r) * (long)ldc + col] = f[r];
            }
        }
    }
}

// ---------------- GEMM256: 256x256 tile, BK=32, 8 waves, 4-deep pipeline, 2-PHASE ------
// C = A(MxK) * BT(NxK)^T. Fragment-major LDS (conflict-free), global_load_lds width 16.
// Per K-tile: phase0 {prefetch issue; read af0/bb; barrier; 16 MFMA} then
// phase1 {read af1; counted vmcnt (guards buf t+1, never 0 mid-loop); barrier; 16 MFMA;
// trailing barrier}. sched_barrier(0) pins each MFMA cluster (reg-only MFMA is NOT
// ordered by asm "memory" — rule: compiler may merge phases otherwise). setprio(1)
// around MFMA clusters gives the CU scheduler role-split arbitration (T5 on T3).
// Buffer-overwrite race is barrier-proven: all reads of buf[t] are lgkm-consumed before
// t's trailing barrier; the overwrite (issue t+4) is emitted after it.
template<int RELU, int SPLIT>
__global__ __launch_bounds__(512, 2)
void gemm256(const uint16_t* __restrict__ A, const uint16_t* __restrict__ BT,
             void* __restrict__ Cv, const float* __restrict__ bias,
             int lda, int ldb, int ldc, int K, int nTn, int S,
             long sstride, int Mst)
{
    __shared__ uint16_t lds[4][16384];   // 4 bufs x (A 16KB + B 16KB)

    // bijective XCD-chunk swizzle (m204), then decode with n-tile fastest.
    const int nb  = (int)gridDim.x;
    const int id  = (int)blockIdx.x;
    const int q   = nb >> 3;
    const int rem = nb & 7;
    const int xcd = id & 7, pos = id >> 3;
    const int wg  = (xcd < rem) ? xcd * (q + 1) + pos
                                : rem * (q + 1) + (xcd - rem) * q + pos;
    const int n_t = wg % nTn;
    const int mz  = wg / nTn;
    const int m_t = mz % MT256;
    const int z   = mz / MT256;

    const long tileM = (long)m_t * 256;
    const long tileN = (long)n_t * 256;

    const int tid  = threadIdx.x;
    const int lane = tid & 63;
    const int wv   = tid >> 6;     // 0..7
    const int wm   = wv >> 2;      // 0..1 (M half)
    const int wn   = wv & 3;       // 0..3 (N quarter)

    // staging: 32 fragment-blocks/buffer (16 A + 16 B), 1KB each; wave wv does blocks j*8+wv.
    // LDS[g*512 + lane*8 + e] = M[tile + (g&15)*16 + (lane&15)][k + ((lane>>4)&3)*8 + e]
    const uint16_t* gsrc[4];
    int doff[4];
    #pragma unroll
    for (int j = 0; j < 4; ++j) {
        int g   = j * 8 + wv;
        int row = (g & 15) * 16 + (lane & 15);
        int kc  = ((lane >> 4) & 3) * 8;
        gsrc[j] = (g < 16) ? (A  + (tileM + row) * (long)lda + kc)
                           : (BT + (tileN + row) * (long)ldb + kc);
        doff[j] = g * 512 + lane * 8;
    }

    const int KT  = K >> 5;                       // K-tiles of 32
    const int kt0 = (int)(((long)z * KT) / S);
    const int kt1 = (int)(((long)(z + 1) * KT) / S);
    const int nt  = kt1 - kt0;
    const long kb = (long)kt0 * 32;

    f4_t acc[8][4];
    #pragma unroll
    for (int mi = 0; mi < 8; ++mi)
        #pragma unroll
        for (int ni = 0; ni < 4; ++ni)
            acc[mi][ni] = {0.0f, 0.0f, 0.0f, 0.0f};

    auto issue = [&](int t) {
        int p   = t & 3;
        long ko = kb + (long)t * 32;
        #pragma unroll
        for (int j = 0; j < 4; ++j)
            __builtin_amdgcn_global_load_lds(
                (__attribute__((address_space(1))) void*)(gsrc[j] + ko),
                (__attribute__((address_space(3))) void*)(&lds[p][doff[j]]),
                16, 0, 0);
    };

    issue(0); issue(1); issue(2);    // prologue: 3 tiles in flight (12 loads/wave)
    asm volatile("s_waitcnt vmcnt(8)" ::: "memory");   // tile 0 landed
    asm volatile("s_barrier" ::: "memory");

    for (int t = 0; t < nt; ++t) {
        const uint16_t* bp = &lds[t & 3][0];

        // -------- phase 0: prefetch issue + af0/bb reads + 16 MFMA --------
        if (t + 3 < nt) issue(t + 3);
        bf16x8 af0[4], bb[4];
        #pragma unroll
        for (int mi = 0; mi < 4; ++mi)
            af0[mi] = *(const bf16x8*)(bp + (wm * 8 + mi) * 512 + lane * 8);
        #pragma unroll
        for (int ni = 0; ni < 4; ++ni)
            bb[ni] = *(const bf16x8*)(bp + 8192 + (wn * 4 + ni) * 512 + lane * 8);
        asm volatile("s_barrier" ::: "memory");
        __builtin_amdgcn_sched_barrier(0);
        __builtin_amdgcn_s_setprio(1);
        #pragma unroll
        for (int mi = 0; mi < 4; ++mi)
            #pragma unroll
            for (int ni = 0; ni < 4; ++ni)
                acc[mi][ni] = __builtin_amdgcn_mfma_f32_16x16x32_bf16(
                    af0[mi], bb[ni], acc[mi][ni], 0, 0, 0);
        __builtin_amdgcn_s_setprio(0);
        __builtin_amdgcn_sched_barrier(0);

        // -------- phase 1: af1 reads + counted vmcnt + 16 MFMA --------
        bf16x8 af1[4];
        #pragma unroll
        for (int mi = 0; mi < 4; ++mi)
            af1[mi] = *(const bf16x8*)(bp + (wm * 8 + 4 + mi) * 512 + lane * 8);
        // guard buf[t+1]: in-flight tiles beyond t are {t+1..min(nt-1,t+3)}
        if (t + 4 <= nt)      asm volatile("s_waitcnt vmcnt(8)" ::: "memory");
        else if (t + 3 == nt) asm volatile("s_waitcnt vmcnt(4)" ::: "memory");
        else if (t + 2 == nt) asm volatile("s_waitcnt vmcnt(0)" ::: "memory");
        asm volatile("s_barrier" ::: "memory");
        __builtin_amdgcn_sched_barrier(0);
        __builtin_amdgcn_s_setprio(1);
        #pragma unroll
        for (int mi = 0; mi < 4; ++mi)
            #pragma unroll
            for (int ni = 0; ni < 4; ++ni)
                acc[4 + mi][ni] = __builtin_amdgcn_mfma_f32_16x16x32_bf16(
                    af1[mi], bb[ni], acc[4 + mi][ni], 0, 0, 0);
        __builtin_amdgcn_s_setprio(0);
        __builtin_amdgcn_sched_barrier(0);
        asm volatile("s_barrier" ::: "memory");   // trailing: buf[t] fully consumed
    }

    // epilogue: row = tileM + wm*128 + mi*16 + (lane>>4)*4 + rr ; col = tileN + wn*64 + ni*16 + (lane&15)
    const int colL = lane & 15;
    const int rowL = ((lane >> 4) & 3) * 4;
    #pragma unroll
    for (int ni = 0; ni < 4; ++ni) {
        long col = tileN + wn * 64 + ni * 16 + colL;
        float bv = 0.0f;
        if (!SPLIT && bias) bv = bias[col];
        #pragma unroll
        for (int mi = 0; mi < 8; ++mi) {
            long row = tileM + wm * 128 + mi * 16 + rowL;
            f4_t v = acc[mi][ni];
            #pragma unroll
            for (int rr = 0; rr < 4; ++rr) {
                if (row + rr < Mst) {
                    float f = v[rr] + bv;
                    if (RELU) f = fmaxf(f, 0.0f);
                    if (SPLIT)
                        ((float*)Cv + (long)z * sstride)[(row + rr) * (long)ldc + col] = f;
                    else
                        ((uint16_t*)Cv)[(row + rr) * (long)ldc + col] = f2bf(f);
                }
            }
        }
    }
}

// ---------------- split-K reduction: sum S partials, +bias, relu, bf16 ----------------
__global__ __launch_bounds__(256)
void reduce_relu(const float* __restrict__ part, const float* __restrict__ bias,
                 uint16_t* __restrict__ h, int logN, int S, long MN)
{
    long base = ((long)blockIdx.x * 256 + threadIdx.x) * 8;
    int col = (int)(base & ((1 << logN) - 1));
    float4 s0 = *(const float4*)(part + base);
    float4 s1 = *(const float4*)(part + base + 4);
    for (int s = 1; s < S; ++s) {
        const float* p = part + (long)s * MN + base;
        float4 a = *(const float4*)p;
        float4 b = *(const float4*)(p + 4);
        s0.x += a.x; s0.y += a.y; s0.z += a.z; s0.w += a.w;
        s1.x += b.x; s1.y += b.y; s1.z += b.z; s1.w += b.w;
    }
    float f[8] = { s0.x, s0.y, s0.z, s0.w, s1.x, s1.y, s1.z, s1.w };
    #pragma unroll
    for (int i = 0; i < 8; ++i)
        f[i] = fmaxf(f[i] + bias[col + i], 0.0f);
    uint4 pk;
    pk.x = (uint32_t)f2bf(f[0]) | ((uint32_t)f2bf(f[1]) << 16);
    pk.y = (uint32_t)f2bf(f[2]) | ((uint32_t)f2bf(f[3]) << 16);
    pk.z = (uint32_t)f2bf(f[4]) | ((uint32_t)f2bf(f[5]) << 16);
    pk.w = (uint32_t)f2bf(f[6]) | ((uint32_t)f2bf(f[7]) << 16);
    *(uint4*)&h[base] = pk;
}

// ---------------- launch ----------------

extern "C" void kernel_launch(void* const* d_in, const int* in_sizes, int n_in,
                              void* d_out, int out_size, void* d_ws, size_t ws_size,
                              hipStream_t stream)
{
    const float* x   = (const float*)d_in[0];
    const float* adj = (const float*)d_in[1];
    const float* W1  = (const float*)d_in[2];
    const float* b1  = (const float*)d_in[3];
    const float* W2  = (const float*)d_in[4];
    const float* b2  = (const float*)d_in[5];
    const float* W3  = (const float*)d_in[6];
    const float* b3  = (const float*)d_in[7];
    const float* Wf  = (const float*)d_in[8];
    const float* bf_ = (const float*)d_in[9];
    float* out = (float*)d_out;

    char* w0 = (char*)d_ws;
    char* w = w0;
    uint16_t* adjb = (uint16_t*)w;  w += (size_t)MP * MP * 2;        // 204.5 MB
    uint16_t* w1t  = (uint16_t*)w;  w += (size_t)512 * 512 * 2;
    uint16_t* w2t  = (uint16_t*)w;  w += (size_t)512 * 512 * 2;
    uint16_t* w3t  = (uint16_t*)w;  w += (size_t)1024 * 512 * 2;
    uint16_t* wft  = (uint16_t*)w;  w += (size_t)256 * 1024 * 2;
    uint16_t* poolP = (uint16_t*)w; w += (size_t)1024 * MP * 2;      // 20.7 MB each
    uint16_t* poolQ = (uint16_t*)w; w += (size_t)1024 * MP * 2;
    uint16_t* poolR = (uint16_t*)w; w += (size_t)1024 * MP * 2;
    float* partial  = (float*)w;
    size_t base_need = (size_t)(w - w0);
    size_t pu = (size_t)MP * 512 * 4;              // 20.7 MB split-unit

    // host-side deterministic split-K config (graph-safe).
    int S12, S3;
    if      (ws_size >= base_need + 6 * pu) { S12 = 3; S3 = 3; }
    else if (ws_size >= base_need + 4 * pu) { S12 = 3; S3 = 2; }
    else if (ws_size >= base_need + 3 * pu) { S12 = 3; S3 = 1; }
    else                                    { S12 = 1; S3 = 1; }

    uint16_t* xb  = poolP;   // MP x 512
    uint16_t* z1t = poolQ;   // 512 x MP
    uint16_t* h1  = poolR;   // MP x 512
    uint16_t* z2t = poolP;   // 512 x MP
    uint16_t* h2  = poolQ;   // MP x 512
    uint16_t* z3t = poolR;   // 1024 x MP
    uint16_t* h3  = poolP;   // MP x 1024

    // conversions
    conv_adj<<<dim3(5, MP), 256, 0, stream>>>(adj, adjb);
    conv_x<<<dim3(MP / 4), 256, 0, stream>>>(x, xb);
    conv_wT<<<dim3(1, 512),  128, 0, stream>>>(W1, w1t, 512, 512);
    conv_wT<<<dim3(1, 512),  128, 0, stream>>>(W2, w2t, 512, 512);
    conv_wT<<<dim3(1, 1024), 128, 0, stream>>>(W3, w3t, 512, 1024);
    conv_wT<<<dim3(1, 256),  128, 0, stream>>>(Wf, wft, 1024, 151);

    const long MN512  = (long)MP * 512;
    const long MN1024 = (long)MP * 1024;

    auto adj_gemm = [&](uint16_t* zt, uint16_t* h, const float* b, int nTn,
                        int N, int logN, int S, long MN) {
        int blocks = MT256 * nTn * S;
        if (S > 1) {
            gemm256<0,1><<<dim3(blocks), 512, 0, stream>>>(
                adjb, zt, partial, nullptr, MP, MP, N, MP, nTn, S, MN, MP);
            reduce_relu<<<dim3((int)(MN / 2048)), 256, 0, stream>>>(partial, b, h, logN, S, MN);
        } else {
            gemm256<1,0><<<dim3(blocks), 512, 0, stream>>>(
                adjb, zt, h, b, MP, MP, N, MP, nTn, 1, 0, MP);
        }
    };

    // layer 1
    gemm_bt<0,1,1,0,0><<<dim3(79, 4), 256, 0, stream>>>(xb, w1t, z1t, nullptr, 512, 512, MP, 512, 0, 0, 0);
    adj_gemm(z1t, h1, b1, 2, 512, 9, S12, MN512);
    // layer 2
    gemm_bt<0,1,1,0,0><<<dim3(79, 4), 256, 0, stream>>>(h1, w2t, z2t, nullptr, 512, 512, MP, 512, 0, 0, 0);
    adj_gemm(z2t, h2, b2, 2, 512, 9, S12, MN512);
    // layer 3 (N = 1024)
    gemm_bt<0,1,1,0,0><<<dim3(79, 8), 256, 0, stream>>>(h2, w3t, z3t, nullptr, 512, 512, MP, 512, 0, 0, 0);
    adj_gemm(z3t, h3, b3, 4, 1024, 10, S3, MN1024);
    // final: out = h3 @ Wf + bf (fp32, guarded 10000 x 151)
    gemm_bt<0,0,0,1,0><<<dim3(79, 2), 256, 0, stream>>>(h3, wft, out, bf_, 1024, 1024, 151, 1024, NR, 151, 0);
}